// Round 7
// baseline (680.887 us; speedup 1.0000x reference)
//
#include <hip/hip_runtime.h>
#include <math.h>

#define KK2 225
#define NPIX 2048
#define OFFC 1800
#define MSKC 900
#define NCOL 2700

// window geometry: 4 adjacent px (same row), taps +-7, |offset|<1
#define WROW 17
#define WCOL 20
#define WPOS (WROW*WCOL)   // 340
#define WSTR 68            // ushort stride per position

// ws layout (float offsets)
#define WS_KW    0
#define WS_XPROJ 16384
#define WS_XDW   (16384+131072)
#define WS_OUT   (16384+2*131072)
#define WS_POOL  (16384+3*131072)
#define WS_GATE  (WS_POOL+128)
#define WS_ENTP  (WS_GATE+128)
#define WS_OFFP  (WS_ENTP+2048)
#define WS_PART2 (WS_OFFP+512)
#define WS_WB    (WS_PART2+4096)        // 86528 floats = Wb[2704][64] bf16
#define WS_DUM   (WS_WB+86528)          // ablation sink region (~20K floats)

typedef __attribute__((ext_vector_type(8))) short short8;
typedef __attribute__((ext_vector_type(4))) float f32x4;

__device__ __forceinline__ float silu(float a) { return a / (1.f + __expf(-a)); }
__device__ __forceinline__ unsigned short f2bf(float f) {
  unsigned u = __float_as_uint(f);
  u += 0x7FFFu + ((u >> 16) & 1u);
  return (unsigned short)(u >> 16);
}
__device__ __forceinline__ float bf2f(unsigned short h) {
  return __uint_as_float(((unsigned)h) << 16);
}

// ---- fused: proj+dwconv (0..511) ; kernel MLP (512..568) ; W->bf16 transpose (569..737) ----
__global__ __launch_bounds__(256) void k_pre(
    const float* __restrict__ x,
    const float* __restrict__ w_ip, const float* __restrict__ b_ip,
    const float* __restrict__ w_dw, const float* __restrict__ b_dw,
    const float* __restrict__ w_pw, const float* __restrict__ b_pw,
    const float* __restrict__ w_k1, const float* __restrict__ b_k1,
    const float* __restrict__ w_k2, const float* __restrict__ b_k2,
    const float* __restrict__ w_k3, const float* __restrict__ b_k3,
    const float* __restrict__ w_off, const float* __restrict__ w_msk,
    float* __restrict__ ws)
{
  int t = threadIdx.x;
  if (blockIdx.x < 512) {
    int px = t >> 6, c = t & 63;
    int pix = blockIdx.x * 4 + px;
    int b = pix >> 10, h = (pix >> 5) & 31, w = pix & 31;
    __shared__ float xs[4][64], ys[4][64];
    xs[px][c] = x[pix*64 + c];
    float acc = b_dw[c];
    #pragma unroll
    for (int dh = -1; dh <= 1; dh++) {
      int hh = h + dh;
      if (hh < 0 || hh > 31) continue;
      #pragma unroll
      for (int dw2 = -1; dw2 <= 1; dw2++) {
        int wp = w + dw2;
        if (wp < 0 || wp > 31) continue;
        acc += x[(((b*32 + hh)*32 + wp) << 6) + c] * w_dw[((dh+1)*3 + (dw2+1))*64 + c];
      }
    }
    ys[px][c] = silu(acc);
    __syncthreads();
    float p1 = b_ip[c], p2 = b_pw[c];
    #pragma unroll 8
    for (int k = 0; k < 64; k++) {
      p1 += xs[px][k] * w_ip[k*64 + c];
      p2 += ys[px][k] * w_pw[k*64 + c];
    }
    ws[WS_XPROJ + pix*64 + c] = p1;
    ws[WS_XDW   + pix*64 + c] = p2;
  } else if (blockIdx.x < 569) {
    __shared__ float h1s[4][32], h2s[4][32];
    int tl = t >> 6, lane = t & 63;
    int tap = (blockIdx.x - 512) * 4 + tl;
    int tapc = min(tap, KK2 - 1);
    int i = tapc / 15, j = tapc % 15;
    float gi = -0.5f + (float)i * (1.0f/14.0f);
    float gj = -0.5f + (float)j * (1.0f/14.0f);
    float p0 = gi * 2.f, p1 = gj * 2.f;
    if (lane < 32) {
      float a = p0 * w_k1[lane] + p1 * w_k1[32 + lane] + b_k1[lane];
      h1s[tl][lane] = silu(a);
    }
    __syncthreads();
    if (lane < 32) {
      float a = b_k2[lane];
      #pragma unroll
      for (int q = 0; q < 32; q++) a += h1s[tl][q] * w_k2[q*32 + lane];
      h2s[tl][lane] = silu(a);
    }
    __syncthreads();
    float a = b_k3[lane];
    #pragma unroll
    for (int q = 0; q < 32; q++) a += h2s[tl][q] * w_k3[q*64 + lane];
    if (tap < KK2) ws[WS_KW + tap*64 + lane] = a;
  } else {
    unsigned short* wb = (unsigned short*)(ws + WS_WB);
    int cb = blockIdx.x - 569;
    int col = cb*16 + (t & 15);
    int kk = (t >> 4) * 4;
    unsigned short v4[4];
    #pragma unroll
    for (int j = 0; j < 4; j++) {
      int k = kk + j;
      float v = 0.f;
      if (col < OFFC)      v = w_off[k*OFFC + col];
      else if (col < NCOL) v = w_msk[k*MSKC + col - OFFC];
      v4[j] = f2bf(v);
    }
    *(uint2*)&wb[(size_t)col*64 + kk] = *(uint2*)v4;
  }
}

// ---- main fused kernel (identical behavior to R6) ----
__global__ __launch_bounds__(1024, 8) void k_main(
    const float* __restrict__ raw_sigma,
    const float* __restrict__ base_scale,
    const float* __restrict__ b_off, const float* __restrict__ b_msk,
    float* __restrict__ ws)
{
  __shared__ unsigned short uni[WPOS*WSTR];
  __shared__ unsigned short off_s[4*OFFC];
  __shared__ float red_s[16];
  __shared__ float ent_sh[16];
  __shared__ float env_sum;

  unsigned short* xbs  = uni;
  unsigned short* mskr = uni + 1152;
  float* env_s = (float*)(uni + 4752);

  int t = threadIdx.x;
  int wv = t >> 6, lane = t & 63;
  int pix0 = blockIdx.x * 4;
  int b = pix0 >> 10;
  int h0 = (pix0 >> 5) & 31, w0 = pix0 & 31;
  const unsigned short* wb = (const unsigned short*)(ws + WS_WB);

  float sp = log1pf(__expf(raw_sigma[0]));
  float sigma = fminf(fmaxf(sp, 1e-3f), 0.5f);
  float envv = 0.f;
  if (t < KK2) {
    int i = t / 15, j = t % 15;
    float gi = -0.5f + (float)i * (1.0f/14.0f);
    float gj = -0.5f + (float)j * (1.0f/14.0f);
    envv = __expf(-(gi*gi + gj*gj) / (2.f*sigma*sigma));
  }
  if (t < 256) {
    int px = t >> 6, k = t & 63;
    xbs[px*72 + k] = f2bf(ws[WS_XDW + (pix0 + px)*64 + k]);
  } else if (t < 1024) {
    int r = t - 256;
    if (r < 768) {
      int px = 4 + (r >> 6), k = r & 63;
      xbs[px*72 + k] = 0;
    }
  }
  {
    float v = envv;
    #pragma unroll
    for (int m = 32; m > 0; m >>= 1) v += __shfl_xor(v, m);
    if (lane == 0) red_s[wv] = v;
    __syncthreads();
    if (t == 0) {
      float s = 0.f;
      #pragma unroll
      for (int q = 0; q < 16; q++) s += red_s[q];
      env_sum = fmaxf(s, 1e-8f);
    }
    __syncthreads();
    if (t < KK2) env_s[t] = envv / env_sum;
  }

  float scale = base_scale[0];
  float offreg = 0.f;
  int pxl = lane & 15;
  int rg = lane >> 4;
  int k0 = rg * 8;
  short8 bfrag_lo = *(const short8*)&xbs[pxl*72 + k0];
  short8 bfrag_hi = *(const short8*)&xbs[pxl*72 + k0 + 32];
  for (int tile = wv; tile < 169; tile += 16) {
    int col0 = tile * 16;
    int m = col0 + pxl;
    const short8 a_lo = *(const short8*)&wb[(size_t)m*64 + k0];
    const short8 a_hi = *(const short8*)&wb[(size_t)m*64 + k0 + 32];
    f32x4 acc = {0.f, 0.f, 0.f, 0.f};
    acc = __builtin_amdgcn_mfma_f32_16x16x32_bf16(a_lo, bfrag_lo, acc, 0, 0, 0);
    acc = __builtin_amdgcn_mfma_f32_16x16x32_bf16(a_hi, bfrag_hi, acc, 0, 0, 0);
    int cg = col0 + rg * 4;
    float4 bias;
    if (cg < OFFC) bias = *(const float4*)&b_off[cg];
    else           bias = *(const float4*)&b_msk[cg - OFFC];
    if (pxl < 4) {
      #pragma unroll
      for (int r = 0; r < 4; r++) {
        int col = cg + r;
        float val = acc[r] + ((const float*)&bias)[r];
        if (col < OFFC) {
          float o = val * scale;
          off_s[pxl*OFFC + col] = f2bf(o);
          offreg += o * o;
        } else if (col < NCOL) {
          mskr[pxl*MSKC + col - OFFC] = f2bf(val);
        }
      }
    }
  }
  {
    #pragma unroll
    for (int m = 32; m > 0; m >>= 1) offreg += __shfl_xor(offreg, m);
    __syncthreads();
    if (lane == 0) red_s[wv] = offreg;
    __syncthreads();
    if (t == 0) {
      float s = 0.f;
      #pragma unroll
      for (int q = 0; q < 16; q++) s += red_s[q];
      ws[WS_OFFP + blockIdx.x] = s;
    }
  }

  int spx = wv >> 2, g = wv & 3;
  float v[4];
  {
    float m = -INFINITY;
    #pragma unroll
    for (int kk = 0; kk < 4; kk++) {
      int p = lane + kk*64;
      if (p < KK2) { v[kk] = bf2f(mskr[spx*MSKC + g*KK2 + p]) * env_s[p]; m = fmaxf(m, v[kk]); }
      else v[kk] = -INFINITY;
    }
    #pragma unroll
    for (int s = 32; s > 0; s >>= 1) m = fmaxf(m, __shfl_xor(m, s));
    float sum = 0.f;
    #pragma unroll
    for (int kk = 0; kk < 4; kk++) {
      int p = lane + kk*64;
      if (p < KK2) { v[kk] = __expf(v[kk] - m); sum += v[kk]; }
    }
    #pragma unroll
    for (int s = 32; s > 0; s >>= 1) sum += __shfl_xor(sum, s);
    float inv = 1.f / sum;
    float ent = 0.f;
    #pragma unroll
    for (int kk = 0; kk < 4; kk++) {
      int p = lane + kk*64;
      if (p < KK2) {
        float a = v[kk] * inv;
        v[kk] = a;
        ent += a * __logf(a + 1e-8f);
      }
    }
    #pragma unroll
    for (int s = 32; s > 0; s >>= 1) ent += __shfl_xor(ent, s);
    if (lane == 0) ent_sh[wv] = ent;
  }
  __syncthreads();
  if (t < 4) ws[WS_ENTP + pix0 + t] =
      ent_sh[t*4] + ent_sh[t*4+1] + ent_sh[t*4+2] + ent_sh[t*4+3];

  {
    const float* xpb = ws + WS_XPROJ + (size_t)(b << 10)*64;
    for (int idx = t; idx < WPOS*8; idx += 1024) {
      int pos = idx >> 3, c8 = idx & 7;
      int r = pos / WCOL, c = pos - r*WCOL;
      int sh = min(max(h0 - 8 + r, 0), 31);
      int sw = min(max(w0 - 8 + c, 0), 31);
      const float* src = xpb + ((sh*32 + sw) << 6) + c8*8;
      float4 f0 = *(const float4*)src;
      float4 f1 = *(const float4*)(src + 4);
      uint2 u01, u23;
      u01.x = ((unsigned)f2bf(f0.y) << 16) | f2bf(f0.x);
      u01.y = ((unsigned)f2bf(f0.w) << 16) | f2bf(f0.z);
      u23.x = ((unsigned)f2bf(f1.y) << 16) | f2bf(f1.x);
      u23.y = ((unsigned)f2bf(f1.w) << 16) | f2bf(f1.z);
      *(uint2*)&uni[pos*WSTR + c8*8]     = u01;
      *(uint2*)&uni[pos*WSTR + c8*8 + 4] = u23;
    }
  }
  __syncthreads();

  {
    int ts = lane >> 2, cl = lane & 3;
    int wpx = w0 + spx;
    int chbase = g*16 + cl*4;
    const float* kwg = ws + WS_KW + g*3600 + cl*4;
    float4 acc = make_float4(0.f, 0.f, 0.f, 0.f);
    #pragma unroll
    for (int kq = 0; kq < 4; kq++) {
      float av = v[kq];
      int nIt = (kq == 3) ? 3 : 4;
      #pragma unroll 1
      for (int i2 = 0; i2 < nIt; i2++) {
        int p = kq*64 + i2*16 + ts;
        if (p < KK2) {
          float at = __shfl(av, i2*16 + ts);
          unsigned op = *(const unsigned*)&off_s[spx*OFFC + g*450 + p*2];
          float o0 = bf2f((unsigned short)(op & 0xFFFFu));
          float o1 = bf2f((unsigned short)(op >> 16));
          int pr = p / 15, pc = p - pr*15;
          float abs_h = (float)(h0 + pr - 7) + o0;
          float abs_w = (float)(wpx + pc - 7) + o1;
          float ah = fminf(fmaxf(abs_h, 0.f), 31.f);
          float aw = fminf(fmaxf(abs_w, 0.f), 31.f);
          int hf = (int)ah;
          int wf = (int)aw;
          float hw_ = ah - (float)hf, ww_ = aw - (float)wf;
          int rf = hf - h0 + 8;
          int rc = min(hf + 1, 31) - h0 + 8;
          int cf = wf - w0 + 8;
          int cc = min(wf + 1, 31) - w0 + 8;
          float s = (abs_h < 0.f || abs_h > 31.f || abs_w < 0.f || abs_w > 31.f) ? 0.f : at;
          float w00 = (1.f-hw_)*(1.f-ww_)*s, w01 = (1.f-hw_)*ww_*s;
          float w10 = hw_*(1.f-ww_)*s,       w11 = hw_*ww_*s;
          uint2 qff = *(const uint2*)&uni[(rf*WCOL + cf)*WSTR + chbase];
          uint2 qfc = *(const uint2*)&uni[(rf*WCOL + cc)*WSTR + chbase];
          uint2 qcf = *(const uint2*)&uni[(rc*WCOL + cf)*WSTR + chbase];
          uint2 qcc = *(const uint2*)&uni[(rc*WCOL + cc)*WSTR + chbase];
          float4 kwv = *(const float4*)&kwg[p*16];
          float ff0 = __uint_as_float(qff.x << 16), ff1 = __uint_as_float(qff.x & 0xFFFF0000u);
          float ff2 = __uint_as_float(qff.y << 16), ff3 = __uint_as_float(qff.y & 0xFFFF0000u);
          float fc0 = __uint_as_float(qfc.x << 16), fc1 = __uint_as_float(qfc.x & 0xFFFF0000u);
          float fc2 = __uint_as_float(qfc.y << 16), fc3 = __uint_as_float(qfc.y & 0xFFFF0000u);
          float cf0 = __uint_as_float(qcf.x << 16), cf1 = __uint_as_float(qcf.x & 0xFFFF0000u);
          float cf2 = __uint_as_float(qcf.y << 16), cf3 = __uint_as_float(qcf.y & 0xFFFF0000u);
          float cc0 = __uint_as_float(qcc.x << 16), cc1 = __uint_as_float(qcc.x & 0xFFFF0000u);
          float cc2 = __uint_as_float(qcc.y << 16), cc3 = __uint_as_float(qcc.y & 0xFFFF0000u);
          acc.x += (ff0*w00 + fc0*w01 + cf0*w10 + cc0*w11) * kwv.x;
          acc.y += (ff1*w00 + fc1*w01 + cf1*w10 + cc1*w11) * kwv.y;
          acc.z += (ff2*w00 + fc2*w01 + cf2*w10 + cc2*w11) * kwv.z;
          acc.w += (ff3*w00 + fc3*w01 + cf3*w10 + cc3*w11) * kwv.w;
        }
      }
    }
    #pragma unroll
    for (int m = 4; m < 64; m <<= 1) {
      acc.x += __shfl_xor(acc.x, m);
      acc.y += __shfl_xor(acc.y, m);
      acc.z += __shfl_xor(acc.z, m);
      acc.w += __shfl_xor(acc.w, m);
    }
    if (lane < 4) *(float4*)&ws[WS_OUT + (pix0 + spx)*64 + g*16 + cl*4] = acc;
  }
}

// ======== ABLATION: prologue + 24x GEMM phase ========
__global__ __launch_bounds__(1024, 8) void k_abl_gemm(
    const float* __restrict__ raw_sigma,
    const float* __restrict__ base_scale,
    const float* __restrict__ b_off, const float* __restrict__ b_msk,
    float* __restrict__ ws)
{
  __shared__ unsigned short uni[WPOS*WSTR];
  __shared__ unsigned short off_s[4*OFFC];
  __shared__ float red_s[16];
  __shared__ float env_sum;
  unsigned short* xbs  = uni;
  unsigned short* mskr = uni + 1152;
  float* env_s = (float*)(uni + 4752);

  int t = threadIdx.x;
  int wv = t >> 6, lane = t & 63;
  int pix0 = blockIdx.x * 4;

  float sp = log1pf(__expf(raw_sigma[0]));
  float sigma = fminf(fmaxf(sp, 1e-3f), 0.5f);
  float envv = 0.f;
  if (t < KK2) {
    int i = t / 15, j = t % 15;
    float gi = -0.5f + (float)i * (1.0f/14.0f);
    float gj = -0.5f + (float)j * (1.0f/14.0f);
    envv = __expf(-(gi*gi + gj*gj) / (2.f*sigma*sigma));
  }
  if (t < 256) {
    int px = t >> 6, k = t & 63;
    xbs[px*72 + k] = f2bf(ws[WS_XDW + (pix0 + px)*64 + k]);
  } else if (t < 1024) {
    int r = t - 256;
    if (r < 768) { int px = 4 + (r >> 6), k = r & 63; xbs[px*72 + k] = 0; }
  }
  {
    float v = envv;
    #pragma unroll
    for (int m = 32; m > 0; m >>= 1) v += __shfl_xor(v, m);
    if (lane == 0) red_s[wv] = v;
    __syncthreads();
    if (t == 0) {
      float s = 0.f;
      #pragma unroll
      for (int q = 0; q < 16; q++) s += red_s[q];
      env_sum = fmaxf(s, 1e-8f);
    }
    __syncthreads();
    if (t < KK2) env_s[t] = envv / env_sum;
  }

  float scale = base_scale[0];
  float snk = 0.f;
  int pxl = lane & 15;
  int rg = lane >> 4;
  int k0 = rg * 8;
  short8 bfrag_lo = *(const short8*)&xbs[pxl*72 + k0];
  short8 bfrag_hi = *(const short8*)&xbs[pxl*72 + k0 + 32];
  #pragma unroll 1
  for (int rep = 0; rep < 24; rep++) {
    const unsigned short* wbl = (const unsigned short*)(ws + WS_WB);
    asm volatile("" : "+v"(wbl));            // opaque pointer: no hoist/CSE across reps
    float offreg = 0.f;
    for (int tile = wv; tile < 169; tile += 16) {
      int col0 = tile * 16;
      int m = col0 + pxl;
      const short8 a_lo = *(const short8*)&wbl[(size_t)m*64 + k0];
      const short8 a_hi = *(const short8*)&wbl[(size_t)m*64 + k0 + 32];
      f32x4 acc = {0.f, 0.f, 0.f, 0.f};
      acc = __builtin_amdgcn_mfma_f32_16x16x32_bf16(a_lo, bfrag_lo, acc, 0, 0, 0);
      acc = __builtin_amdgcn_mfma_f32_16x16x32_bf16(a_hi, bfrag_hi, acc, 0, 0, 0);
      int cg = col0 + rg * 4;
      float4 bias;
      if (cg < OFFC) bias = *(const float4*)&b_off[cg];
      else           bias = *(const float4*)&b_msk[cg - OFFC];
      if (pxl < 4) {
        #pragma unroll
        for (int r = 0; r < 4; r++) {
          int col = cg + r;
          float val = acc[r] + ((const float*)&bias)[r];
          if (col < OFFC) {
            float o = val * scale;
            off_s[pxl*OFFC + col] = f2bf(o);
            offreg += o * o;
          } else if (col < NCOL) {
            mskr[pxl*MSKC + col - OFFC] = f2bf(val);
          }
        }
      }
    }
    snk += offreg;
  }
  __syncthreads();
  snk += bf2f(off_s[(t*7) % (4*OFFC)]) + bf2f(mskr[(t*11) % (4*MSKC)]) + env_s[t % KK2];
  #pragma unroll
  for (int m = 32; m > 0; m >>= 1) snk += __shfl_xor(snk, m);
  if (lane == 0) ws[WS_DUM + blockIdx.x*16 + wv] = snk;
}

// ======== ABLATION: prologue + 1x GEMM + 48x softmax ========
__global__ __launch_bounds__(1024, 8) void k_abl_sm(
    const float* __restrict__ raw_sigma,
    const float* __restrict__ base_scale,
    const float* __restrict__ b_off, const float* __restrict__ b_msk,
    float* __restrict__ ws)
{
  __shared__ unsigned short uni[WPOS*WSTR];
  __shared__ unsigned short off_s[4*OFFC];
  __shared__ float red_s[16];
  __shared__ float ent_sh[16];
  __shared__ float env_sum;
  unsigned short* xbs  = uni;
  unsigned short* mskr = uni + 1152;
  float* env_s = (float*)(uni + 4752);

  int t = threadIdx.x;
  int wv = t >> 6, lane = t & 63;
  int pix0 = blockIdx.x * 4;
  const unsigned short* wb = (const unsigned short*)(ws + WS_WB);

  float sp = log1pf(__expf(raw_sigma[0]));
  float sigma = fminf(fmaxf(sp, 1e-3f), 0.5f);
  float envv = 0.f;
  if (t < KK2) {
    int i = t / 15, j = t % 15;
    float gi = -0.5f + (float)i * (1.0f/14.0f);
    float gj = -0.5f + (float)j * (1.0f/14.0f);
    envv = __expf(-(gi*gi + gj*gj) / (2.f*sigma*sigma));
  }
  if (t < 256) {
    int px = t >> 6, k = t & 63;
    xbs[px*72 + k] = f2bf(ws[WS_XDW + (pix0 + px)*64 + k]);
  } else if (t < 1024) {
    int r = t - 256;
    if (r < 768) { int px = 4 + (r >> 6), k = r & 63; xbs[px*72 + k] = 0; }
  }
  {
    float v = envv;
    #pragma unroll
    for (int m = 32; m > 0; m >>= 1) v += __shfl_xor(v, m);
    if (lane == 0) red_s[wv] = v;
    __syncthreads();
    if (t == 0) {
      float s = 0.f;
      #pragma unroll
      for (int q = 0; q < 16; q++) s += red_s[q];
      env_sum = fmaxf(s, 1e-8f);
    }
    __syncthreads();
    if (t < KK2) env_s[t] = envv / env_sum;
  }

  float scale = base_scale[0];
  float snk = 0.f;
  int pxl = lane & 15;
  int rg = lane >> 4;
  int k0 = rg * 8;
  short8 bfrag_lo = *(const short8*)&xbs[pxl*72 + k0];
  short8 bfrag_hi = *(const short8*)&xbs[pxl*72 + k0 + 32];
  for (int tile = wv; tile < 169; tile += 16) {
    int col0 = tile * 16;
    int m = col0 + pxl;
    const short8 a_lo = *(const short8*)&wb[(size_t)m*64 + k0];
    const short8 a_hi = *(const short8*)&wb[(size_t)m*64 + k0 + 32];
    f32x4 acc = {0.f, 0.f, 0.f, 0.f};
    acc = __builtin_amdgcn_mfma_f32_16x16x32_bf16(a_lo, bfrag_lo, acc, 0, 0, 0);
    acc = __builtin_amdgcn_mfma_f32_16x16x32_bf16(a_hi, bfrag_hi, acc, 0, 0, 0);
    int cg = col0 + rg * 4;
    float4 bias;
    if (cg < OFFC) bias = *(const float4*)&b_off[cg];
    else           bias = *(const float4*)&b_msk[cg - OFFC];
    if (pxl < 4) {
      #pragma unroll
      for (int r = 0; r < 4; r++) {
        int col = cg + r;
        float val = acc[r] + ((const float*)&bias)[r];
        if (col < OFFC) {
          float o = val * scale;
          off_s[pxl*OFFC + col] = f2bf(o);
          snk += o * o;
        } else if (col < NCOL) {
          mskr[pxl*MSKC + col - OFFC] = f2bf(val);
        }
      }
    }
  }
  __syncthreads();

  int spx = wv >> 2, g = wv & 3;
  float v[4] = {0.f, 0.f, 0.f, 0.f};
  #pragma unroll 1
  for (int rep = 0; rep < 48; rep++) {
    const unsigned short* ml = mskr;
    asm volatile("" : "+v"(ml));             // opaque: re-read each rep
    float m = -INFINITY;
    #pragma unroll
    for (int kk = 0; kk < 4; kk++) {
      int p = lane + kk*64;
      if (p < KK2) { v[kk] = bf2f(ml[spx*MSKC + g*KK2 + p]) * env_s[p]; m = fmaxf(m, v[kk]); }
      else v[kk] = -INFINITY;
    }
    #pragma unroll
    for (int s = 32; s > 0; s >>= 1) m = fmaxf(m, __shfl_xor(m, s));
    float sum = 0.f;
    #pragma unroll
    for (int kk = 0; kk < 4; kk++) {
      int p = lane + kk*64;
      if (p < KK2) { v[kk] = __expf(v[kk] - m); sum += v[kk]; }
    }
    #pragma unroll
    for (int s = 32; s > 0; s >>= 1) sum += __shfl_xor(sum, s);
    float inv = 1.f / sum;
    float ent = 0.f;
    #pragma unroll
    for (int kk = 0; kk < 4; kk++) {
      int p = lane + kk*64;
      if (p < KK2) {
        float a = v[kk] * inv;
        v[kk] = a;
        ent += a * __logf(a + 1e-8f);
      }
    }
    #pragma unroll
    for (int s = 32; s > 0; s >>= 1) ent += __shfl_xor(ent, s);
    if (lane == 0) ent_sh[wv] = ent;
    snk += v[0] + v[3];
  }
  __syncthreads();
  if (t < 4) ws[WS_DUM + 16896 + pix0 + t] =
      ent_sh[t*4] + ent_sh[t*4+1] + ent_sh[t*4+2] + ent_sh[t*4+3];
  snk += bf2f(off_s[(t*7) % (4*OFFC)]);
  #pragma unroll
  for (int m = 32; m > 0; m >>= 1) snk += __shfl_xor(snk, m);
  if (lane == 0) ws[WS_DUM + 8704 + blockIdx.x*16 + wv] = snk;
}

// ---- parallel reductions ----
__global__ __launch_bounds__(256) void k_red(float* __restrict__ ws, float* __restrict__ d_out)
{
  __shared__ float red[256];
  int t = threadIdx.x, blk = blockIdx.x;
  if (blk < 64) {
    int b = blk >> 5, chunk = blk & 31;
    int c = t & 63, str = t >> 6;
    const float* base = ws + WS_OUT + (size_t)((b*1024 + chunk*32) << 6) + c;
    float s = 0.f;
    #pragma unroll
    for (int i = 0; i < 8; i++) s += base[((str + i*4) << 6)];
    red[t] = s;
    __syncthreads();
    if (t < 64) ws[WS_PART2 + blk*64 + t] =
      red[t] + red[t+64] + red[t+128] + red[t+192];
  } else if (blk == 64) {
    float s = 0.f;
    #pragma unroll
    for (int i = 0; i < 8; i++) s += ws[WS_ENTP + t + i*256];
    #pragma unroll
    for (int m = 32; m > 0; m >>= 1) s += __shfl_xor(s, m);
    if ((t & 63) == 0) red[t >> 6] = s;
    __syncthreads();
    if (t == 0) d_out[NPIX*64 + 1] = (red[0] + red[1] + red[2] + red[3]) * (1.f/8192.f);
  } else {
    float s = 0.f;
    #pragma unroll
    for (int i = 0; i < 2; i++) s += ws[WS_OFFP + t + i*256];
    #pragma unroll
    for (int m = 32; m > 0; m >>= 1) s += __shfl_xor(s, m);
    if ((t & 63) == 0) red[t >> 6] = s;
    __syncthreads();
    if (t == 0) d_out[NPIX*64] = (red[0] + red[1] + red[2] + red[3]) * (1.f/3686400.f);
  }
}

// ---- SE gate ----
__global__ __launch_bounds__(128) void k_se(
    const float* __restrict__ w_fc1, const float* __restrict__ b_fc1,
    const float* __restrict__ w_fc2, const float* __restrict__ b_fc2,
    float* __restrict__ ws)
{
  __shared__ float pool_s[2][64];
  __shared__ float hsh[2][16];
  int t = threadIdx.x;
  int b = t >> 6, c = t & 63;
  {
    float s = 0.f;
    #pragma unroll
    for (int ch = 0; ch < 32; ch++) s += ws[WS_PART2 + (b*32 + ch)*64 + c];
    pool_s[b][c] = s * (1.f/1024.f);
  }
  __syncthreads();
  if (t < 32) {
    int bb = t >> 4, r = t & 15;
    float a = b_fc1[r];
    #pragma unroll 16
    for (int cc = 0; cc < 64; cc++) a += pool_s[bb][cc] * w_fc1[cc*16 + r];
    hsh[bb][r] = silu(a);
  }
  __syncthreads();
  float a = b_fc2[c];
  #pragma unroll
  for (int r = 0; r < 16; r++) a += hsh[b][r] * w_fc2[r*64 + c];
  ws[WS_GATE + b*64 + c] = 1.f / (1.f + __expf(-a));
}

__global__ __launch_bounds__(256) void k_final(
    const float* __restrict__ w_op, const float* __restrict__ b_op,
    const float* __restrict__ ws, float* __restrict__ d_out)
{
  int t = threadIdx.x;
  int px = t >> 6, c = t & 63;
  int pix = blockIdx.x * 4 + px;
  int b = pix >> 10;
  __shared__ float sc[4][64];
  sc[px][c] = ws[WS_OUT + pix*64 + c] * ws[WS_GATE + b*64 + c];
  __syncthreads();
  float a = b_op[c];
  #pragma unroll 8
  for (int k = 0; k < 64; k++) a += sc[px][k] * w_op[k*64 + c];
  d_out[pix*64 + c] = a;
}

extern "C" void kernel_launch(void* const* d_in, const int* in_sizes, int n_in,
                              void* d_out, int out_size, void* d_ws, size_t ws_size,
                              hipStream_t stream)
{
  const float* x     = (const float*)d_in[0];
  const float* rsig  = (const float*)d_in[1];
  const float* bos   = (const float*)d_in[2];
  const float* w_ip  = (const float*)d_in[3];
  const float* b_ip  = (const float*)d_in[4];
  const float* w_op  = (const float*)d_in[5];
  const float* b_op  = (const float*)d_in[6];
  const float* w_dw  = (const float*)d_in[7];
  const float* b_dw  = (const float*)d_in[8];
  const float* w_pw  = (const float*)d_in[9];
  const float* b_pw  = (const float*)d_in[10];
  const float* w_off = (const float*)d_in[11];
  const float* b_off = (const float*)d_in[12];
  const float* w_msk = (const float*)d_in[13];
  const float* b_msk = (const float*)d_in[14];
  const float* w_k1  = (const float*)d_in[15];
  const float* b_k1  = (const float*)d_in[16];
  const float* w_k2  = (const float*)d_in[17];
  const float* b_k2  = (const float*)d_in[18];
  const float* w_k3  = (const float*)d_in[19];
  const float* b_k3  = (const float*)d_in[20];
  const float* w_fc1 = (const float*)d_in[21];
  const float* b_fc1 = (const float*)d_in[22];
  const float* w_fc2 = (const float*)d_in[23];
  const float* b_fc2 = (const float*)d_in[24];
  float* ws  = (float*)d_ws;
  float* out = (float*)d_out;

  hipLaunchKernelGGL(k_pre, dim3(738), dim3(256), 0, stream,
                     x, w_ip, b_ip, w_dw, b_dw, w_pw, b_pw,
                     w_k1, b_k1, w_k2, b_k2, w_k3, b_k3, w_off, w_msk, ws);
  hipLaunchKernelGGL(k_main, dim3(512), dim3(1024), 0, stream,
                     rsig, bos, b_off, b_msk, ws);
  hipLaunchKernelGGL(k_abl_gemm, dim3(512), dim3(1024), 0, stream,
                     rsig, bos, b_off, b_msk, ws);
  hipLaunchKernelGGL(k_abl_sm, dim3(512), dim3(1024), 0, stream,
                     rsig, bos, b_off, b_msk, ws);
  hipLaunchKernelGGL(k_red, dim3(66), dim3(256), 0, stream, ws, out);
  hipLaunchKernelGGL(k_se, dim3(1), dim3(128), 0, stream,
                     w_fc1, b_fc1, w_fc2, b_fc2, ws);
  hipLaunchKernelGGL(k_final, dim3(512), dim3(256), 0, stream,
                     w_op, b_op, ws, out);
}

// Round 8
// 59.226 us; speedup vs baseline: 11.4964x; 11.4964x over previous
//
#include <hip/hip_runtime.h>
#include <math.h>

#define KK2 225
#define NPIX 2048
#define OFFC 1800
#define MSKC 900
#define NCOL 2700
#define NCOLP 2704
#define HSTR 2704            // hd row stride (ushorts)

// window geometry: 4 adjacent px (same row), taps +-7, |offset|<1
#define WROW 17
#define WCOL 20
#define WPOS (WROW*WCOL)   // 340
#define WSTR 68            // ushort stride per position

// ws layout (float offsets)
#define WS_KW    0                      // 14400 f32 (kernel MLP out)
#define WS_XPROJ 16384                  // x_proj bf16 [2048][64] (131072 ush in 65536 f32 slots)
#define WS_XB    (16384+131072)         // x_dw bf16 [2048][64]
#define WS_OUT   (16384+2*131072)       // 131072 f32 (deform output)
#define WS_POOL  (16384+3*131072)
#define WS_GATE  (WS_POOL+128)
#define WS_ENTP  (WS_GATE+128)          // 2048
#define WS_OFFP  (WS_ENTP+2048)         // 512
#define WS_PART2 (WS_OFFP+512)          // 4096
#define WS_WB    (WS_PART2+4096)        // 86528 f32 = Wb[2704][64] bf16
#define WS_HD    (WS_WB+86528)          // head out bf16 [2048][2704] = 2770944 f32

typedef __attribute__((ext_vector_type(8))) short short8;
typedef __attribute__((ext_vector_type(4))) float f32x4;

__device__ __forceinline__ float silu(float a) { return a / (1.f + __expf(-a)); }
__device__ __forceinline__ unsigned short f2bf(float f) {
  unsigned u = __float_as_uint(f);
  u += 0x7FFFu + ((u >> 16) & 1u);
  return (unsigned short)(u >> 16);
}
__device__ __forceinline__ float bf2f(unsigned short h) {
  return __uint_as_float(((unsigned)h) << 16);
}

// ---- fused: proj+dwconv (0..511) ; kernel MLP (512..568) ; W->bf16 transpose (569..737) ----
__global__ __launch_bounds__(256) void k_pre(
    const float* __restrict__ x,
    const float* __restrict__ w_ip, const float* __restrict__ b_ip,
    const float* __restrict__ w_dw, const float* __restrict__ b_dw,
    const float* __restrict__ w_pw, const float* __restrict__ b_pw,
    const float* __restrict__ w_k1, const float* __restrict__ b_k1,
    const float* __restrict__ w_k2, const float* __restrict__ b_k2,
    const float* __restrict__ w_k3, const float* __restrict__ b_k3,
    const float* __restrict__ w_off, const float* __restrict__ w_msk,
    float* __restrict__ ws)
{
  int t = threadIdx.x;
  if (blockIdx.x < 512) {
    int px = t >> 6, c = t & 63;
    int pix = blockIdx.x * 4 + px;
    int b = pix >> 10, h = (pix >> 5) & 31, w = pix & 31;
    __shared__ float xs[4][64], ys[4][64];
    xs[px][c] = x[pix*64 + c];
    float acc = b_dw[c];
    #pragma unroll
    for (int dh = -1; dh <= 1; dh++) {
      int hh = h + dh;
      if (hh < 0 || hh > 31) continue;
      #pragma unroll
      for (int dw2 = -1; dw2 <= 1; dw2++) {
        int wp = w + dw2;
        if (wp < 0 || wp > 31) continue;
        acc += x[(((b*32 + hh)*32 + wp) << 6) + c] * w_dw[((dh+1)*3 + (dw2+1))*64 + c];
      }
    }
    ys[px][c] = silu(acc);
    __syncthreads();
    float p1 = b_ip[c], p2 = b_pw[c];
    #pragma unroll 8
    for (int k = 0; k < 64; k++) {
      p1 += xs[px][k] * w_ip[k*64 + c];
      p2 += ys[px][k] * w_pw[k*64 + c];
    }
    ((unsigned short*)(ws + WS_XPROJ))[pix*64 + c] = f2bf(p1);
    ((unsigned short*)(ws + WS_XB))[pix*64 + c]    = f2bf(p2);
  } else if (blockIdx.x < 569) {
    __shared__ float h1s[4][32], h2s[4][32];
    int tl = t >> 6, lane = t & 63;
    int tap = (blockIdx.x - 512) * 4 + tl;
    int tapc = min(tap, KK2 - 1);
    int i = tapc / 15, j = tapc % 15;
    float gi = -0.5f + (float)i * (1.0f/14.0f);
    float gj = -0.5f + (float)j * (1.0f/14.0f);
    float p0 = gi * 2.f, p1 = gj * 2.f;
    if (lane < 32) {
      float a = p0 * w_k1[lane] + p1 * w_k1[32 + lane] + b_k1[lane];
      h1s[tl][lane] = silu(a);
    }
    __syncthreads();
    if (lane < 32) {
      float a = b_k2[lane];
      #pragma unroll
      for (int q = 0; q < 32; q++) a += h1s[tl][q] * w_k2[q*32 + lane];
      h2s[tl][lane] = silu(a);
    }
    __syncthreads();
    float a = b_k3[lane];
    #pragma unroll
    for (int q = 0; q < 32; q++) a += h2s[tl][q] * w_k3[q*64 + lane];
    if (tap < KK2) ws[WS_KW + tap*64 + lane] = a;
  } else {
    unsigned short* wb = (unsigned short*)(ws + WS_WB);
    int cb = blockIdx.x - 569;
    int col = cb*16 + (t & 15);
    int kk = (t >> 4) * 4;
    unsigned short v4[4];
    #pragma unroll
    for (int j = 0; j < 4; j++) {
      int k = kk + j;
      float v = 0.f;
      if (col < OFFC)      v = w_off[k*OFFC + col];
      else if (col < NCOL) v = w_msk[k*MSKC + col - OFFC];
      v4[j] = f2bf(v);
    }
    *(uint2*)&wb[(size_t)col*64 + kk] = *(uint2*)v4;
  }
}

// ---- head GEMM: A = x_dw [2048][64] bf16, B = Wb [2704][64] bf16, C -> hd bf16 ----
// block = 256 thr (4 waves): 64 px x 64 cols. grid (43, 32).
__global__ __launch_bounds__(256) void k_gemm(
    const float* __restrict__ base_scale,
    const float* __restrict__ b_off, const float* __restrict__ b_msk,
    float* __restrict__ ws)
{
  int t = threadIdx.x;
  int wv = t >> 6, lane = t & 63;
  int row = lane & 15, rg = lane >> 4;
  int k0 = rg * 8;
  int colb = blockIdx.x * 64;
  int pxb  = blockIdx.y * 64 + wv * 16;
  const unsigned short* xb = (const unsigned short*)(ws + WS_XB);
  const unsigned short* wb = (const unsigned short*)(ws + WS_WB);
  unsigned short* hd = (unsigned short*)(ws + WS_HD);
  float scale = base_scale[0];

  short8 a_lo = *(const short8*)&xb[(size_t)(pxb + row)*64 + k0];
  short8 a_hi = *(const short8*)&xb[(size_t)(pxb + row)*64 + k0 + 32];
  #pragma unroll
  for (int ct = 0; ct < 4; ct++) {
    int c0 = colb + ct*16;
    if (c0 >= NCOLP) break;
    const short8 b_lo = *(const short8*)&wb[(size_t)(c0 + row)*64 + k0];
    const short8 b_hi = *(const short8*)&wb[(size_t)(c0 + row)*64 + k0 + 32];
    f32x4 acc = {0.f, 0.f, 0.f, 0.f};
    acc = __builtin_amdgcn_mfma_f32_16x16x32_bf16(a_lo, b_lo, acc, 0, 0, 0);
    acc = __builtin_amdgcn_mfma_f32_16x16x32_bf16(a_hi, b_hi, acc, 0, 0, 0);
    int col = c0 + row;                 // D col (n) = lane&15
    float bias = 0.f, mult = 1.f;
    if (col < OFFC)      { bias = b_off[col]; mult = scale; }
    else if (col < NCOL) { bias = b_msk[col - OFFC]; }
    #pragma unroll
    for (int r = 0; r < 4; r++) {
      int px = pxb + rg*4 + r;          // D row (m)
      hd[(size_t)px*HSTR + col] = f2bf((acc[r] + bias) * mult);
    }
  }
}

// ---- sampling kernel: env + window stage + softmax + deform sampling ----
__global__ __launch_bounds__(1024, 8) void k_samp(
    const float* __restrict__ raw_sigma,
    float* __restrict__ ws)
{
  __shared__ unsigned short uni[WPOS*WSTR];   // 46240 B window
  __shared__ float env_s[KK2];
  __shared__ float red_s[16];
  __shared__ float ent_sh[16];
  __shared__ float env_sum;

  int t = threadIdx.x;
  int wv = t >> 6, lane = t & 63;
  int pix0 = blockIdx.x * 4;
  int b = pix0 >> 10;
  int h0 = (pix0 >> 5) & 31, w0 = pix0 & 31;
  const unsigned short* hd = (const unsigned short*)(ws + WS_HD);

  // env
  float sp = log1pf(__expf(raw_sigma[0]));
  float sigma = fminf(fmaxf(sp, 1e-3f), 0.5f);
  float envv = 0.f;
  if (t < KK2) {
    int i = t / 15, j = t % 15;
    float gi = -0.5f + (float)i * (1.0f/14.0f);
    float gj = -0.5f + (float)j * (1.0f/14.0f);
    envv = __expf(-(gi*gi + gj*gj) / (2.f*sigma*sigma));
  }
  {
    float v = envv;
    #pragma unroll
    for (int m = 32; m > 0; m >>= 1) v += __shfl_xor(v, m);
    if (lane == 0) red_s[wv] = v;
    __syncthreads();
    if (t == 0) {
      float s = 0.f;
      #pragma unroll
      for (int q = 0; q < 16; q++) s += red_s[q];
      env_sum = fmaxf(s, 1e-8f);
    }
    __syncthreads();
    if (t < KK2) env_s[t] = envv / env_sum;
  }

  // window staging: straight bf16 copies from x_proj(bf16) -> uni[pos][68]
  {
    const unsigned short* xpb = (const unsigned short*)(ws + WS_XPROJ) + ((size_t)(b << 10) << 6);
    for (int idx = t; idx < WPOS*16; idx += 1024) {
      int pos = idx >> 4, c4 = idx & 15;     // 4-channel chunks (8B)
      int r = pos / WCOL, c = pos - r*WCOL;
      int sh = min(max(h0 - 8 + r, 0), 31);
      int sw = min(max(w0 - 8 + c, 0), 31);
      uint2 u = *(const uint2*)&xpb[((sh*32 + sw) << 6) + c4*4];
      *(uint2*)&uni[pos*WSTR + c4*4] = u;
    }
  }

  // softmax: wave wv = (px,g); mask logits straight from hd (coalesced)
  int spx = wv >> 2, g = wv & 3;
  const unsigned short* hrow = hd + (size_t)(pix0 + spx)*HSTR;
  float v[4];
  {
    float m = -INFINITY;
    #pragma unroll
    for (int kk = 0; kk < 4; kk++) {
      int p = lane + kk*64;
      if (p < KK2) { v[kk] = bf2f(hrow[OFFC + g*KK2 + p]) * env_s[p]; m = fmaxf(m, v[kk]); }
      else v[kk] = -INFINITY;
    }
    #pragma unroll
    for (int s = 32; s > 0; s >>= 1) m = fmaxf(m, __shfl_xor(m, s));
    float sum = 0.f;
    #pragma unroll
    for (int kk = 0; kk < 4; kk++) {
      int p = lane + kk*64;
      if (p < KK2) { v[kk] = __expf(v[kk] - m); sum += v[kk]; }
    }
    #pragma unroll
    for (int s = 32; s > 0; s >>= 1) sum += __shfl_xor(sum, s);
    float inv = 1.f / sum;
    float ent = 0.f;
    #pragma unroll
    for (int kk = 0; kk < 4; kk++) {
      int p = lane + kk*64;
      if (p < KK2) {
        float a = v[kk] * inv;
        v[kk] = a;
        ent += a * __logf(a + 1e-8f);
      }
    }
    #pragma unroll
    for (int s = 32; s > 0; s >>= 1) ent += __shfl_xor(ent, s);
    if (lane == 0) ent_sh[wv] = ent;
  }
  __syncthreads();   // window + ent_sh ready
  if (t < 4) ws[WS_ENTP + pix0 + t] =
      ent_sh[t*4] + ent_sh[t*4+1] + ent_sh[t*4+2] + ent_sh[t*4+3];

  // sampling from LDS window; offsets from hd; offreg folded in (cl==0 lanes)
  float offreg = 0.f;
  {
    int ts = lane >> 2, cl = lane & 3;
    int wpx = w0 + spx;
    int chbase = g*16 + cl*4;
    const float* kwg = ws + WS_KW + g*3600 + cl*4;
    float4 acc = make_float4(0.f, 0.f, 0.f, 0.f);
    #pragma unroll
    for (int kq = 0; kq < 4; kq++) {
      float av = v[kq];
      int nIt = (kq == 3) ? 3 : 4;
      #pragma unroll 1
      for (int i2 = 0; i2 < nIt; i2++) {
        int p = kq*64 + i2*16 + ts;
        if (p < KK2) {
          float at = __shfl(av, i2*16 + ts);
          unsigned op = *(const unsigned*)&hrow[g*450 + p*2];
          float o0 = bf2f((unsigned short)(op & 0xFFFFu));
          float o1 = bf2f((unsigned short)(op >> 16));
          if (cl == 0) offreg += o0*o0 + o1*o1;
          int pr = p / 15, pc = p - pr*15;
          float abs_h = (float)(h0 + pr - 7) + o0;
          float abs_w = (float)(wpx + pc - 7) + o1;
          float ah = fminf(fmaxf(abs_h, 0.f), 31.f);
          float aw = fminf(fmaxf(abs_w, 0.f), 31.f);
          int hf = (int)ah;
          int wf = (int)aw;
          float hw_ = ah - (float)hf, ww_ = aw - (float)wf;
          int rf = hf - h0 + 8;
          int rc = min(hf + 1, 31) - h0 + 8;
          int cf = wf - w0 + 8;
          int cc = min(wf + 1, 31) - w0 + 8;
          float s = (abs_h < 0.f || abs_h > 31.f || abs_w < 0.f || abs_w > 31.f) ? 0.f : at;
          float w00 = (1.f-hw_)*(1.f-ww_)*s, w01 = (1.f-hw_)*ww_*s;
          float w10 = hw_*(1.f-ww_)*s,       w11 = hw_*ww_*s;
          uint2 qff = *(const uint2*)&uni[(rf*WCOL + cf)*WSTR + chbase];
          uint2 qfc = *(const uint2*)&uni[(rf*WCOL + cc)*WSTR + chbase];
          uint2 qcf = *(const uint2*)&uni[(rc*WCOL + cf)*WSTR + chbase];
          uint2 qcc = *(const uint2*)&uni[(rc*WCOL + cc)*WSTR + chbase];
          float4 kwv = *(const float4*)&kwg[p*16];
          float ff0 = __uint_as_float(qff.x << 16), ff1 = __uint_as_float(qff.x & 0xFFFF0000u);
          float ff2 = __uint_as_float(qff.y << 16), ff3 = __uint_as_float(qff.y & 0xFFFF0000u);
          float fc0 = __uint_as_float(qfc.x << 16), fc1 = __uint_as_float(qfc.x & 0xFFFF0000u);
          float fc2 = __uint_as_float(qfc.y << 16), fc3 = __uint_as_float(qfc.y & 0xFFFF0000u);
          float cf0 = __uint_as_float(qcf.x << 16), cf1 = __uint_as_float(qcf.x & 0xFFFF0000u);
          float cf2 = __uint_as_float(qcf.y << 16), cf3 = __uint_as_float(qcf.y & 0xFFFF0000u);
          float cc0 = __uint_as_float(qcc.x << 16), cc1 = __uint_as_float(qcc.x & 0xFFFF0000u);
          float cc2 = __uint_as_float(qcc.y << 16), cc3 = __uint_as_float(qcc.y & 0xFFFF0000u);
          acc.x += (ff0*w00 + fc0*w01 + cf0*w10 + cc0*w11) * kwv.x;
          acc.y += (ff1*w00 + fc1*w01 + cf1*w10 + cc1*w11) * kwv.y;
          acc.z += (ff2*w00 + fc2*w01 + cf2*w10 + cc2*w11) * kwv.z;
          acc.w += (ff3*w00 + fc3*w01 + cf3*w10 + cc3*w11) * kwv.w;
        }
      }
    }
    #pragma unroll
    for (int m = 4; m < 64; m <<= 1) {
      acc.x += __shfl_xor(acc.x, m);
      acc.y += __shfl_xor(acc.y, m);
      acc.z += __shfl_xor(acc.z, m);
      acc.w += __shfl_xor(acc.w, m);
    }
    if (lane < 4) *(float4*)&ws[WS_OUT + (pix0 + spx)*64 + g*16 + cl*4] = acc;
  }
  // offreg block reduce
  {
    #pragma unroll
    for (int m = 32; m > 0; m >>= 1) offreg += __shfl_xor(offreg, m);
    if (lane == 0) red_s[wv] = offreg;
    __syncthreads();
    if (t == 0) {
      float s = 0.f;
      #pragma unroll
      for (int q = 0; q < 16; q++) s += red_s[q];
      ws[WS_OFFP + blockIdx.x] = s;
    }
  }
}

// ---- parallel reductions ----
__global__ __launch_bounds__(256) void k_red(float* __restrict__ ws, float* __restrict__ d_out)
{
  __shared__ float red[256];
  int t = threadIdx.x, blk = blockIdx.x;
  if (blk < 64) {
    int b = blk >> 5, chunk = blk & 31;
    int c = t & 63, str = t >> 6;
    const float* base = ws + WS_OUT + (size_t)((b*1024 + chunk*32) << 6) + c;
    float s = 0.f;
    #pragma unroll
    for (int i = 0; i < 8; i++) s += base[((str + i*4) << 6)];
    red[t] = s;
    __syncthreads();
    if (t < 64) ws[WS_PART2 + blk*64 + t] =
      red[t] + red[t+64] + red[t+128] + red[t+192];
  } else if (blk == 64) {
    float s = 0.f;
    #pragma unroll
    for (int i = 0; i < 8; i++) s += ws[WS_ENTP + t + i*256];
    #pragma unroll
    for (int m = 32; m > 0; m >>= 1) s += __shfl_xor(s, m);
    if ((t & 63) == 0) red[t >> 6] = s;
    __syncthreads();
    if (t == 0) d_out[NPIX*64 + 1] = (red[0] + red[1] + red[2] + red[3]) * (1.f/8192.f);
  } else {
    float s = 0.f;
    #pragma unroll
    for (int i = 0; i < 2; i++) s += ws[WS_OFFP + t + i*256];
    #pragma unroll
    for (int m = 32; m > 0; m >>= 1) s += __shfl_xor(s, m);
    if ((t & 63) == 0) red[t >> 6] = s;
    __syncthreads();
    if (t == 0) d_out[NPIX*64] = (red[0] + red[1] + red[2] + red[3]) * (1.f/3686400.f);
  }
}

// ---- SE gate ----
__global__ __launch_bounds__(128) void k_se(
    const float* __restrict__ w_fc1, const float* __restrict__ b_fc1,
    const float* __restrict__ w_fc2, const float* __restrict__ b_fc2,
    float* __restrict__ ws)
{
  __shared__ float pool_s[2][64];
  __shared__ float hsh[2][16];
  int t = threadIdx.x;
  int b = t >> 6, c = t & 63;
  {
    float s = 0.f;
    #pragma unroll
    for (int ch = 0; ch < 32; ch++) s += ws[WS_PART2 + (b*32 + ch)*64 + c];
    pool_s[b][c] = s * (1.f/1024.f);
  }
  __syncthreads();
  if (t < 32) {
    int bb = t >> 4, r = t & 15;
    float a = b_fc1[r];
    #pragma unroll 16
    for (int cc = 0; cc < 64; cc++) a += pool_s[bb][cc] * w_fc1[cc*16 + r];
    hsh[bb][r] = silu(a);
  }
  __syncthreads();
  float a = b_fc2[c];
  #pragma unroll
  for (int r = 0; r < 16; r++) a += hsh[b][r] * w_fc2[r*64 + c];
  ws[WS_GATE + b*64 + c] = 1.f / (1.f + __expf(-a));
}

__global__ __launch_bounds__(256) void k_final(
    const float* __restrict__ w_op, const float* __restrict__ b_op,
    const float* __restrict__ ws, float* __restrict__ d_out)
{
  int t = threadIdx.x;
  int px = t >> 6, c = t & 63;
  int pix = blockIdx.x * 4 + px;
  int b = pix >> 10;
  __shared__ float sc[4][64];
  sc[px][c] = ws[WS_OUT + pix*64 + c] * ws[WS_GATE + b*64 + c];
  __syncthreads();
  float a = b_op[c];
  #pragma unroll 8
  for (int k = 0; k < 64; k++) a += sc[px][k] * w_op[k*64 + c];
  d_out[pix*64 + c] = a;
}

extern "C" void kernel_launch(void* const* d_in, const int* in_sizes, int n_in,
                              void* d_out, int out_size, void* d_ws, size_t ws_size,
                              hipStream_t stream)
{
  const float* x     = (const float*)d_in[0];
  const float* rsig  = (const float*)d_in[1];
  const float* bos   = (const float*)d_in[2];
  const float* w_ip  = (const float*)d_in[3];
  const float* b_ip  = (const float*)d_in[4];
  const float* w_op  = (const float*)d_in[5];
  const float* b_op  = (const float*)d_in[6];
  const float* w_dw  = (const float*)d_in[7];
  const float* b_dw  = (const float*)d_in[8];
  const float* w_pw  = (const float*)d_in[9];
  const float* b_pw  = (const float*)d_in[10];
  const float* w_off = (const float*)d_in[11];
  const float* b_off = (const float*)d_in[12];
  const float* w_msk = (const float*)d_in[13];
  const float* b_msk = (const float*)d_in[14];
  const float* w_k1  = (const float*)d_in[15];
  const float* b_k1  = (const float*)d_in[16];
  const float* w_k2  = (const float*)d_in[17];
  const float* b_k2  = (const float*)d_in[18];
  const float* w_k3  = (const float*)d_in[19];
  const float* b_k3  = (const float*)d_in[20];
  const float* w_fc1 = (const float*)d_in[21];
  const float* b_fc1 = (const float*)d_in[22];
  const float* w_fc2 = (const float*)d_in[23];
  const float* b_fc2 = (const float*)d_in[24];
  float* ws  = (float*)d_ws;
  float* out = (float*)d_out;

  hipLaunchKernelGGL(k_pre, dim3(738), dim3(256), 0, stream,
                     x, w_ip, b_ip, w_dw, b_dw, w_pw, b_pw,
                     w_k1, b_k1, w_k2, b_k2, w_k3, b_k3, w_off, w_msk, ws);
  hipLaunchKernelGGL(k_gemm, dim3(43, 32), dim3(256), 0, stream,
                     bos, b_off, b_msk, ws);
  hipLaunchKernelGGL(k_samp, dim3(512), dim3(1024), 0, stream,
                     rsig, ws);
  hipLaunchKernelGGL(k_red, dim3(66), dim3(256), 0, stream, ws, out);
  hipLaunchKernelGGL(k_se, dim3(1), dim3(128), 0, stream,
                     w_fc1, b_fc1, w_fc2, b_fc2, ws);
  hipLaunchKernelGGL(k_final, dim3(512), dim3(256), 0, stream,
                     w_op, b_op, ws, out);
}

// Round 9
// 56.642 us; speedup vs baseline: 12.0209x; 1.0456x over previous
//
#include <hip/hip_runtime.h>
#include <math.h>

#define KK2 225
#define NPIX 2048
#define OFFC 1800
#define MSKC 900
#define NCOL 2700
#define NCOLP 2704
#define HSTR 2704            // hd row stride (ushorts)

// window geometry: 4 adjacent px (same row), taps +-7, |offset|<1
#define WROW 17
#define WCOL 20
#define WPOS (WROW*WCOL)   // 340
#define WSTR 68            // ushort stride per position

// ws layout (float offsets)
#define WS_KWB   0                      // kw bf16 [g*3600+p*16+c] : 14400 ush = 7200 f32
#define WS_XPROJ 16384                  // x_proj bf16 [2048][64]
#define WS_XB    81920                  // x_dw bf16 [2048][64]
#define WS_OUT   147456                 // deform out f32 [2048][64]
#define WS_GATE  278528                 // 128
#define WS_ENTP  278656                 // 2048
#define WS_OFFP  280704                 // 512
#define WS_PART2 281216                 // pooled partials f32 [512][64]
#define WS_WB    313984                 // Wb bf16 [2704][64] : 86528 f32
#define WS_HD    400512                 // hd bf16 [2048][2704]

typedef __attribute__((ext_vector_type(8))) short short8;
typedef __attribute__((ext_vector_type(4))) float f32x4;

__device__ __forceinline__ float silu(float a) { return a / (1.f + __expf(-a)); }
__device__ __forceinline__ unsigned short f2bf(float f) {
  unsigned u = __float_as_uint(f);
  u += 0x7FFFu + ((u >> 16) & 1u);
  return (unsigned short)(u >> 16);
}
__device__ __forceinline__ float bf2f(unsigned short h) {
  return __uint_as_float(((unsigned)h) << 16);
}

// ---- fused: proj+dwconv (0..511) ; kernel MLP (512..568) ; W->bf16 transpose (569..737) ----
__global__ __launch_bounds__(256) void k_pre(
    const float* __restrict__ x,
    const float* __restrict__ w_ip, const float* __restrict__ b_ip,
    const float* __restrict__ w_dw, const float* __restrict__ b_dw,
    const float* __restrict__ w_pw, const float* __restrict__ b_pw,
    const float* __restrict__ w_k1, const float* __restrict__ b_k1,
    const float* __restrict__ w_k2, const float* __restrict__ b_k2,
    const float* __restrict__ w_k3, const float* __restrict__ b_k3,
    const float* __restrict__ w_off, const float* __restrict__ w_msk,
    float* __restrict__ ws)
{
  int t = threadIdx.x;
  if (blockIdx.x < 512) {
    int px = t >> 6, c = t & 63;
    int pix = blockIdx.x * 4 + px;
    int b = pix >> 10, h = (pix >> 5) & 31, w = pix & 31;
    __shared__ float xs[4][64], ys[4][64];
    xs[px][c] = x[pix*64 + c];
    float acc = b_dw[c];
    #pragma unroll
    for (int dh = -1; dh <= 1; dh++) {
      int hh = h + dh;
      if (hh < 0 || hh > 31) continue;
      #pragma unroll
      for (int dw2 = -1; dw2 <= 1; dw2++) {
        int wp = w + dw2;
        if (wp < 0 || wp > 31) continue;
        acc += x[(((b*32 + hh)*32 + wp) << 6) + c] * w_dw[((dh+1)*3 + (dw2+1))*64 + c];
      }
    }
    ys[px][c] = silu(acc);
    __syncthreads();
    float p1 = b_ip[c], p2 = b_pw[c];
    #pragma unroll 8
    for (int k = 0; k < 64; k++) {
      p1 += xs[px][k] * w_ip[k*64 + c];
      p2 += ys[px][k] * w_pw[k*64 + c];
    }
    ((unsigned short*)(ws + WS_XPROJ))[pix*64 + c] = f2bf(p1);
    ((unsigned short*)(ws + WS_XB))[pix*64 + c]    = f2bf(p2);
  } else if (blockIdx.x < 569) {
    __shared__ float h1s[4][32], h2s[4][32];
    int tl = t >> 6, lane = t & 63;
    int tap = (blockIdx.x - 512) * 4 + tl;
    int tapc = min(tap, KK2 - 1);
    int i = tapc / 15, j = tapc % 15;
    float gi = -0.5f + (float)i * (1.0f/14.0f);
    float gj = -0.5f + (float)j * (1.0f/14.0f);
    float p0 = gi * 2.f, p1 = gj * 2.f;
    if (lane < 32) {
      float a = p0 * w_k1[lane] + p1 * w_k1[32 + lane] + b_k1[lane];
      h1s[tl][lane] = silu(a);
    }
    __syncthreads();
    if (lane < 32) {
      float a = b_k2[lane];
      #pragma unroll
      for (int q = 0; q < 32; q++) a += h1s[tl][q] * w_k2[q*32 + lane];
      h2s[tl][lane] = silu(a);
    }
    __syncthreads();
    float a = b_k3[lane];
    #pragma unroll
    for (int q = 0; q < 32; q++) a += h2s[tl][q] * w_k3[q*64 + lane];
    // torch-view quirk: kwb flat[g*3600+p*16+c] == flat[tap*64+lane]
    if (tap < KK2) ((unsigned short*)(ws + WS_KWB))[tap*64 + lane] = f2bf(a);
  } else {
    unsigned short* wb = (unsigned short*)(ws + WS_WB);
    int cb = blockIdx.x - 569;
    int col = cb*16 + (t & 15);
    int kk = (t >> 4) * 4;
    unsigned short v4[4];
    #pragma unroll
    for (int j = 0; j < 4; j++) {
      int k = kk + j;
      float v = 0.f;
      if (col < OFFC)      v = w_off[k*OFFC + col];
      else if (col < NCOL) v = w_msk[k*MSKC + col - OFFC];
      v4[j] = f2bf(v);
    }
    *(uint2*)&wb[(size_t)col*64 + kk] = *(uint2*)v4;
  }
}

// ---- head GEMM: A = x_dw [2048][64] bf16, B = Wb [2704][64] bf16, C -> hd bf16 ----
__global__ __launch_bounds__(256) void k_gemm(
    const float* __restrict__ base_scale,
    const float* __restrict__ b_off, const float* __restrict__ b_msk,
    float* __restrict__ ws)
{
  int t = threadIdx.x;
  int wv = t >> 6, lane = t & 63;
  int row = lane & 15, rg = lane >> 4;
  int k0 = rg * 8;
  int colb = blockIdx.x * 64;
  int pxb  = blockIdx.y * 64 + wv * 16;
  const unsigned short* xb = (const unsigned short*)(ws + WS_XB);
  const unsigned short* wb = (const unsigned short*)(ws + WS_WB);
  unsigned short* hd = (unsigned short*)(ws + WS_HD);
  float scale = base_scale[0];

  short8 a_lo = *(const short8*)&xb[(size_t)(pxb + row)*64 + k0];
  short8 a_hi = *(const short8*)&xb[(size_t)(pxb + row)*64 + k0 + 32];
  #pragma unroll
  for (int ct = 0; ct < 4; ct++) {
    int c0 = colb + ct*16;
    if (c0 >= NCOLP) break;
    const short8 b_lo = *(const short8*)&wb[(size_t)(c0 + row)*64 + k0];
    const short8 b_hi = *(const short8*)&wb[(size_t)(c0 + row)*64 + k0 + 32];
    f32x4 acc = {0.f, 0.f, 0.f, 0.f};
    acc = __builtin_amdgcn_mfma_f32_16x16x32_bf16(a_lo, b_lo, acc, 0, 0, 0);
    acc = __builtin_amdgcn_mfma_f32_16x16x32_bf16(a_hi, b_hi, acc, 0, 0, 0);
    int col = c0 + row;
    float bias = 0.f, mult = 1.f;
    if (col < OFFC)      { bias = b_off[col]; mult = scale; }
    else if (col < NCOL) { bias = b_msk[col - OFFC]; }
    #pragma unroll
    for (int r = 0; r < 4; r++) {
      int px = pxb + rg*4 + r;
      hd[(size_t)px*HSTR + col] = f2bf((acc[r] + bias) * mult);
    }
  }
}

// ---- sampling: env + off/window LDS stage + softmax + deform sampling + pooled partial ----
__global__ __launch_bounds__(1024, 8) void k_samp(
    const float* __restrict__ raw_sigma,
    float* __restrict__ ws)
{
  __shared__ unsigned short uni[WPOS*WSTR];   // 46240 B window
  __shared__ unsigned short off_s[4*OFFC];    // 14400 B offsets bf16
  __shared__ float po_s[4][64];               // 1 KB pooled partial
  __shared__ float env_s[KK2];
  __shared__ float red_s[16];
  __shared__ float ent_sh[16];
  __shared__ float env_sum;

  int t = threadIdx.x;
  int wv = t >> 6, lane = t & 63;
  int pix0 = blockIdx.x * 4;
  int b = pix0 >> 10;
  int h0 = (pix0 >> 5) & 31, w0 = pix0 & 31;
  const unsigned short* hd = (const unsigned short*)(ws + WS_HD);

  // --- env ---
  float sp = log1pf(__expf(raw_sigma[0]));
  float sigma = fminf(fmaxf(sp, 1e-3f), 0.5f);
  float envv = 0.f;
  if (t < KK2) {
    int i = t / 15, j = t % 15;
    float gi = -0.5f + (float)i * (1.0f/14.0f);
    float gj = -0.5f + (float)j * (1.0f/14.0f);
    envv = __expf(-(gi*gi + gj*gj) / (2.f*sigma*sigma));
  }
  {
    float v = envv;
    #pragma unroll
    for (int m = 32; m > 0; m >>= 1) v += __shfl_xor(v, m);
    if (lane == 0) red_s[wv] = v;
    __syncthreads();
    if (t == 0) {
      float s = 0.f;
      #pragma unroll
      for (int q = 0; q < 16; q++) s += red_s[q];
      env_sum = fmaxf(s, 1e-8f);
    }
    __syncthreads();
    if (t < KK2) env_s[t] = envv / env_sum;
  }

  // --- stage offsets hd[pix][0:1800] -> LDS (coalesced 8B), fold offreg ---
  float offreg = 0.f;
  {
    for (int idx = t; idx < 1800; idx += 1024) {     // 1800 uint2 chunks
      int px = idx / 450, q = idx - px*450;
      uint2 u = *(const uint2*)&hd[(size_t)(pix0 + px)*HSTR + q*4];
      *(uint2*)&off_s[px*OFFC + q*4] = u;
      float o0 = bf2f((unsigned short)(u.x & 0xFFFFu));
      float o1 = bf2f((unsigned short)(u.x >> 16));
      float o2 = bf2f((unsigned short)(u.y & 0xFFFFu));
      float o3 = bf2f((unsigned short)(u.y >> 16));
      offreg += o0*o0 + o1*o1 + o2*o2 + o3*o3;
    }
    #pragma unroll
    for (int m = 32; m > 0; m >>= 1) offreg += __shfl_xor(offreg, m);
    if (lane == 0) red_s[wv] = offreg;
  }

  // --- stage bilinear window x_proj -> uni ---
  {
    const unsigned short* xpb = (const unsigned short*)(ws + WS_XPROJ) + ((size_t)(b << 10) << 6);
    for (int idx = t; idx < WPOS*16; idx += 1024) {
      int pos = idx >> 4, c4 = idx & 15;
      int r = pos / WCOL, c = pos - r*WCOL;
      int sh = min(max(h0 - 8 + r, 0), 31);
      int sw = min(max(w0 - 8 + c, 0), 31);
      uint2 u = *(const uint2*)&xpb[((sh*32 + sw) << 6) + c4*4];
      *(uint2*)&uni[pos*WSTR + c4*4] = u;
    }
  }
  __syncthreads();   // env_s, off_s, uni, red_s(offreg) all visible
  if (t == 0) {
    float s = 0.f;
    #pragma unroll
    for (int q = 0; q < 16; q++) s += red_s[q];
    ws[WS_OFFP + blockIdx.x] = s;
  }

  // --- softmax: wave wv = (px,g); attn stays in regs ---
  int spx = wv >> 2, g = wv & 3;
  const unsigned short* hrow = hd + (size_t)(pix0 + spx)*HSTR;
  float v[4];
  {
    float m = -INFINITY;
    #pragma unroll
    for (int kk = 0; kk < 4; kk++) {
      int p = lane + kk*64;
      if (p < KK2) { v[kk] = bf2f(hrow[OFFC + g*KK2 + p]) * env_s[p]; m = fmaxf(m, v[kk]); }
      else v[kk] = -INFINITY;
    }
    #pragma unroll
    for (int s = 32; s > 0; s >>= 1) m = fmaxf(m, __shfl_xor(m, s));
    float sum = 0.f;
    #pragma unroll
    for (int kk = 0; kk < 4; kk++) {
      int p = lane + kk*64;
      if (p < KK2) { v[kk] = __expf(v[kk] - m); sum += v[kk]; }
    }
    #pragma unroll
    for (int s = 32; s > 0; s >>= 1) sum += __shfl_xor(sum, s);
    float inv = 1.f / sum;
    float ent = 0.f;
    #pragma unroll
    for (int kk = 0; kk < 4; kk++) {
      int p = lane + kk*64;
      if (p < KK2) {
        float a = v[kk] * inv;
        v[kk] = a;
        ent += a * __logf(a + 1e-8f);
      }
    }
    #pragma unroll
    for (int s = 32; s > 0; s >>= 1) ent += __shfl_xor(ent, s);
    if (lane == 0) ent_sh[wv] = ent;
  }

  // --- sampling from LDS: 16 tap-streams x 4 ch-quads, pipelined taps ---
  {
    int ts = lane >> 2, cl = lane & 3;
    int wpx = w0 + spx;
    int chbase = g*16 + cl*4;
    const unsigned short* kwb = (const unsigned short*)(ws + WS_KWB);
    int kwbase = g*3600 + cl*4;
    float4 acc = make_float4(0.f, 0.f, 0.f, 0.f);
    #pragma unroll 5
    for (int k = 0; k < 15; k++) {
      int p = ts + k*16;
      if (p < KK2) {
        float at = __shfl(v[k >> 2], ts + ((k & 3) << 4));
        unsigned op = *(const unsigned*)&off_s[spx*OFFC + g*450 + p*2];
        float o0 = bf2f((unsigned short)(op & 0xFFFFu));
        float o1 = bf2f((unsigned short)(op >> 16));
        int pr = p / 15, pc = p - pr*15;
        float abs_h = (float)(h0 + pr - 7) + o0;
        float abs_w = (float)(wpx + pc - 7) + o1;
        float ah = fminf(fmaxf(abs_h, 0.f), 31.f);
        float aw = fminf(fmaxf(abs_w, 0.f), 31.f);
        int hf = (int)ah;
        int wf = (int)aw;
        float hw_ = ah - (float)hf, ww_ = aw - (float)wf;
        int rf = hf - h0 + 8;
        int rc = min(hf + 1, 31) - h0 + 8;
        int cf = wf - w0 + 8;
        int cc = min(wf + 1, 31) - w0 + 8;
        float s = (abs_h < 0.f || abs_h > 31.f || abs_w < 0.f || abs_w > 31.f) ? 0.f : at;
        float w00 = (1.f-hw_)*(1.f-ww_)*s, w01 = (1.f-hw_)*ww_*s;
        float w10 = hw_*(1.f-ww_)*s,       w11 = hw_*ww_*s;
        uint2 qff = *(const uint2*)&uni[(rf*WCOL + cf)*WSTR + chbase];
        uint2 qfc = *(const uint2*)&uni[(rf*WCOL + cc)*WSTR + chbase];
        uint2 qcf = *(const uint2*)&uni[(rc*WCOL + cf)*WSTR + chbase];
        uint2 qcc = *(const uint2*)&uni[(rc*WCOL + cc)*WSTR + chbase];
        uint2 kq = *(const uint2*)&kwb[kwbase + p*16];
        float kw0 = bf2f((unsigned short)(kq.x & 0xFFFFu));
        float kw1 = bf2f((unsigned short)(kq.x >> 16));
        float kw2 = bf2f((unsigned short)(kq.y & 0xFFFFu));
        float kw3 = bf2f((unsigned short)(kq.y >> 16));
        float ff0 = __uint_as_float(qff.x << 16), ff1 = __uint_as_float(qff.x & 0xFFFF0000u);
        float ff2 = __uint_as_float(qff.y << 16), ff3 = __uint_as_float(qff.y & 0xFFFF0000u);
        float fc0 = __uint_as_float(qfc.x << 16), fc1 = __uint_as_float(qfc.x & 0xFFFF0000u);
        float fc2 = __uint_as_float(qfc.y << 16), fc3 = __uint_as_float(qfc.y & 0xFFFF0000u);
        float cf0 = __uint_as_float(qcf.x << 16), cf1 = __uint_as_float(qcf.x & 0xFFFF0000u);
        float cf2 = __uint_as_float(qcf.y << 16), cf3 = __uint_as_float(qcf.y & 0xFFFF0000u);
        float cc0 = __uint_as_float(qcc.x << 16), cc1 = __uint_as_float(qcc.x & 0xFFFF0000u);
        float cc2 = __uint_as_float(qcc.y << 16), cc3 = __uint_as_float(qcc.y & 0xFFFF0000u);
        acc.x += (ff0*w00 + fc0*w01 + cf0*w10 + cc0*w11) * kw0;
        acc.y += (ff1*w00 + fc1*w01 + cf1*w10 + cc1*w11) * kw1;
        acc.z += (ff2*w00 + fc2*w01 + cf2*w10 + cc2*w11) * kw2;
        acc.w += (ff3*w00 + fc3*w01 + cf3*w10 + cc3*w11) * kw3;
      }
    }
    #pragma unroll
    for (int m = 4; m < 64; m <<= 1) {
      acc.x += __shfl_xor(acc.x, m);
      acc.y += __shfl_xor(acc.y, m);
      acc.z += __shfl_xor(acc.z, m);
      acc.w += __shfl_xor(acc.w, m);
    }
    if (lane < 4) {
      *(float4*)&ws[WS_OUT + (pix0 + spx)*64 + g*16 + cl*4] = acc;
      *(float4*)&po_s[spx][g*16 + cl*4] = acc;
    }
  }
  __syncthreads();
  if (t < 64) ws[WS_PART2 + blockIdx.x*64 + t] =
      po_s[0][t] + po_s[1][t] + po_s[2][t] + po_s[3][t];
  if (t < 4) ws[WS_ENTP + pix0 + t] =
      ent_sh[t*4] + ent_sh[t*4+1] + ent_sh[t*4+2] + ent_sh[t*4+3];
}

// ---- SE gate + all final reductions (1 block, 1024 thr) ----
__global__ __launch_bounds__(1024) void k_se(
    const float* __restrict__ w_fc1, const float* __restrict__ b_fc1,
    const float* __restrict__ w_fc2, const float* __restrict__ b_fc2,
    float* __restrict__ ws, float* __restrict__ d_out)
{
  __shared__ float redm[16][64];
  __shared__ float pool_s[2][64];
  __shared__ float hsh[2][16];
  __shared__ float rscal[32];
  int t = threadIdx.x;
  int wv = t >> 6, lane = t & 63;
  int c = lane;           // wait: pooled uses c = t&63
  // pooled stage-2: part[512][64]; grp = wv: b = wv&1, seg = wv>>1
  {
    int b = wv & 1, seg = wv >> 1;
    float s = 0.f;
    #pragma unroll
    for (int i = 0; i < 32; i++)
      s += ws[WS_PART2 + (((b*256 + seg*32 + i) << 6) + c)];
    redm[wv][c] = s;
  }
  // entropy (2048) + offreg (512) partials
  {
    float e = ws[WS_ENTP + t] + ws[WS_ENTP + t + 1024];
    float o = (t < 512) ? ws[WS_OFFP + t] : 0.f;
    #pragma unroll
    for (int m = 32; m > 0; m >>= 1) { e += __shfl_xor(e, m); o += __shfl_xor(o, m); }
    if (lane == 0) { rscal[wv] = e; rscal[16 + wv] = o; }
  }
  __syncthreads();
  if (t < 128) {
    int bb = t >> 6, cc = t & 63;
    float s2 = 0.f;
    #pragma unroll
    for (int seg = 0; seg < 8; seg++) s2 += redm[seg*2 + bb][cc];
    pool_s[bb][cc] = s2 * (1.f/1024.f);
  }
  if (t == 0) {
    float se_ = 0.f, so = 0.f;
    #pragma unroll
    for (int q = 0; q < 16; q++) { se_ += rscal[q]; so += rscal[16 + q]; }
    d_out[NPIX*64 + 1] = se_ * (1.f/8192.f);     // -entropy
    d_out[NPIX*64]     = so  * (1.f/3686400.f);  // offset_reg
  }
  __syncthreads();
  if (t < 32) {
    int bb = t >> 4, r = t & 15;
    float a = b_fc1[r];
    #pragma unroll 16
    for (int cc = 0; cc < 64; cc++) a += pool_s[bb][cc] * w_fc1[cc*16 + r];
    hsh[bb][r] = silu(a);
  }
  __syncthreads();
  if (t < 128) {
    int bb = t >> 6, cc = t & 63;
    float a = b_fc2[cc];
    #pragma unroll
    for (int r = 0; r < 16; r++) a += hsh[bb][r] * w_fc2[r*64 + cc];
    ws[WS_GATE + bb*64 + cc] = 1.f / (1.f + __expf(-a));
  }
}

__global__ __launch_bounds__(256) void k_final(
    const float* __restrict__ w_op, const float* __restrict__ b_op,
    const float* __restrict__ ws, float* __restrict__ d_out)
{
  int t = threadIdx.x;
  int px = t >> 6, c = t & 63;
  int pix = blockIdx.x * 4 + px;
  int b = pix >> 10;
  __shared__ float sc[4][64];
  sc[px][c] = ws[WS_OUT + pix*64 + c] * ws[WS_GATE + b*64 + c];
  __syncthreads();
  float a = b_op[c];
  #pragma unroll 8
  for (int k = 0; k < 64; k++) a += sc[px][k] * w_op[k*64 + c];
  d_out[pix*64 + c] = a;
}

extern "C" void kernel_launch(void* const* d_in, const int* in_sizes, int n_in,
                              void* d_out, int out_size, void* d_ws, size_t ws_size,
                              hipStream_t stream)
{
  const float* x     = (const float*)d_in[0];
  const float* rsig  = (const float*)d_in[1];
  const float* bos   = (const float*)d_in[2];
  const float* w_ip  = (const float*)d_in[3];
  const float* b_ip  = (const float*)d_in[4];
  const float* w_op  = (const float*)d_in[5];
  const float* b_op  = (const float*)d_in[6];
  const float* w_dw  = (const float*)d_in[7];
  const float* b_dw  = (const float*)d_in[8];
  const float* w_pw  = (const float*)d_in[9];
  const float* b_pw  = (const float*)d_in[10];
  const float* w_off = (const float*)d_in[11];
  const float* b_off = (const float*)d_in[12];
  const float* w_msk = (const float*)d_in[13];
  const float* b_msk = (const float*)d_in[14];
  const float* w_k1  = (const float*)d_in[15];
  const float* b_k1  = (const float*)d_in[16];
  const float* w_k2  = (const float*)d_in[17];
  const float* b_k2  = (const float*)d_in[18];
  const float* w_k3  = (const float*)d_in[19];
  const float* b_k3  = (const float*)d_in[20];
  const float* w_fc1 = (const float*)d_in[21];
  const float* b_fc1 = (const float*)d_in[22];
  const float* w_fc2 = (const float*)d_in[23];
  const float* b_fc2 = (const float*)d_in[24];
  float* ws  = (float*)d_ws;
  float* out = (float*)d_out;

  hipLaunchKernelGGL(k_pre, dim3(738), dim3(256), 0, stream,
                     x, w_ip, b_ip, w_dw, b_dw, w_pw, b_pw,
                     w_k1, b_k1, w_k2, b_k2, w_k3, b_k3, w_off, w_msk, ws);
  hipLaunchKernelGGL(k_gemm, dim3(43, 32), dim3(256), 0, stream,
                     bos, b_off, b_msk, ws);
  hipLaunchKernelGGL(k_samp, dim3(512), dim3(1024), 0, stream,
                     rsig, ws);
  hipLaunchKernelGGL(k_se, dim3(1), dim3(1024), 0, stream,
                     w_fc1, b_fc1, w_fc2, b_fc2, ws, out);
  hipLaunchKernelGGL(k_final, dim3(512), dim3(256), 0, stream,
                     w_op, b_op, ws, out);
}